// Round 1
// baseline (1162.072 us; speedup 1.0000x reference)
//
#include <hip/hip_runtime.h>
#include <math.h>

// ---------------------------------------------------------------------------
// KeyActionRetrieval: cosine top-k retrieval.
//   sims[i] = (keys[i]·q) / max(||keys[i]|| * ||q||, 1e-8)
//   idx     = top_k(sims, 8)   (descending, ties -> lower index)
//   out     = actions[idx]     ([8,7] fp32)
// Memory-bound on the single pass over keys (819.2 MB).
// ---------------------------------------------------------------------------

__global__ __launch_bounds__(256) void qnorm_kernel(const float* __restrict__ q,
                                                    int D,
                                                    float* __restrict__ out) {
    float ss = 0.f;
    for (int i = threadIdx.x; i < D; i += 256) {
        float v = q[i];
        ss = fmaf(v, v, ss);
    }
#pragma unroll
    for (int off = 32; off; off >>= 1) ss += __shfl_down(ss, off);
    __shared__ float wsum[4];
    if ((threadIdx.x & 63) == 0) wsum[threadIdx.x >> 6] = ss;
    __syncthreads();
    if (threadIdx.x == 0) out[0] = sqrtf(wsum[0] + wsum[1] + wsum[2] + wsum[3]);
}

// One wave (64 lanes) per row; D=2048 -> 8 float4 per lane, coalesced 1KB/inst.
// q preloaded into 8 float4 registers per lane, reused across rows.
__global__ __launch_bounds__(256) void sims2048_kernel(const float* __restrict__ q,
                                                       const float* __restrict__ keys,
                                                       const float* __restrict__ qnorm_p,
                                                       float* __restrict__ sims,
                                                       int N) {
    const int lane   = threadIdx.x & 63;
    const int wave   = (blockIdx.x * blockDim.x + threadIdx.x) >> 6;
    const int nwaves = (gridDim.x * blockDim.x) >> 6;
    const float qnorm = qnorm_p[0];

    const float4* __restrict__ q4 = (const float4*)q;
    float4 qv[8];
#pragma unroll
    for (int k = 0; k < 8; ++k) qv[k] = q4[k * 64 + lane];

    for (int row = wave; row < N; row += nwaves) {
        const float4* __restrict__ k4 = (const float4*)(keys + (size_t)row * 2048);
        float dot = 0.f, ss = 0.f;
#pragma unroll
        for (int k = 0; k < 8; ++k) {
            float4 kv = k4[k * 64 + lane];
            dot = fmaf(kv.x, qv[k].x, dot);
            dot = fmaf(kv.y, qv[k].y, dot);
            dot = fmaf(kv.z, qv[k].z, dot);
            dot = fmaf(kv.w, qv[k].w, dot);
            ss = fmaf(kv.x, kv.x, ss);
            ss = fmaf(kv.y, kv.y, ss);
            ss = fmaf(kv.z, kv.z, ss);
            ss = fmaf(kv.w, kv.w, ss);
        }
#pragma unroll
        for (int off = 32; off; off >>= 1) {
            dot += __shfl_down(dot, off);
            ss  += __shfl_down(ss, off);
        }
        if (lane == 0) sims[row] = dot / fmaxf(sqrtf(ss) * qnorm, 1e-8f);
    }
}

// Generic fallback for D != 2048 (correctness path only).
__global__ void sims_generic_kernel(const float* __restrict__ q,
                                    const float* __restrict__ keys,
                                    const float* __restrict__ qnorm_p,
                                    float* __restrict__ sims,
                                    int N, int D) {
    const int lane   = threadIdx.x & 63;
    const int wave   = (blockIdx.x * blockDim.x + threadIdx.x) >> 6;
    const int nwaves = (gridDim.x * blockDim.x) >> 6;
    const float qnorm = qnorm_p[0];
    for (int row = wave; row < N; row += nwaves) {
        const float* kr = keys + (size_t)row * D;
        float dot = 0.f, ss = 0.f;
        for (int j = lane; j < D; j += 64) {
            float kv = kr[j];
            dot = fmaf(kv, q[j], dot);
            ss  = fmaf(kv, kv, ss);
        }
        for (int off = 32; off; off >>= 1) {
            dot += __shfl_down(dot, off);
            ss  += __shfl_down(ss, off);
        }
        if (lane == 0) sims[row] = dot / fmaxf(sqrtf(ss) * qnorm, 1e-8f);
    }
}

// Single block: per-thread sorted top-8 (registers, fully unrolled insertion),
// spill to LDS, 8 rounds of block argmax (tie: lower index), gather actions.
#define TK_THREADS 512
__global__ __launch_bounds__(TK_THREADS) void topk_kernel(const float* __restrict__ sims,
                                                          const float* __restrict__ actions,
                                                          float* __restrict__ out,
                                                          int N, int A, int K) {
    const int t    = threadIdx.x;
    const int lane = t & 63;
    const int wid  = t >> 6;

    __shared__ float lv[TK_THREADS * 8];
    __shared__ int   li[TK_THREADS * 8];
    __shared__ float wbv[TK_THREADS / 64];
    __shared__ int   wbi[TK_THREADS / 64];
    __shared__ int   winner;
    __shared__ int   res[8];

    float bv[8];
    int   bi[8];
#pragma unroll
    for (int j = 0; j < 8; ++j) { bv[j] = -INFINITY; bi[j] = 0x7fffffff; }

    // local top-8 over strided slice (float4 main path; per-thread i ascending)
    const int n4 = N >> 2;
    const float4* __restrict__ s4 = (const float4*)sims;
    for (int i = t; i < n4; i += TK_THREADS) {
        float4 v = s4[i];
        float vv[4] = {v.x, v.y, v.z, v.w};
#pragma unroll
        for (int c = 0; c < 4; ++c) {
            float cv = vv[c];
            int   ci = 4 * i + c;
            if (cv > bv[7] || (cv == bv[7] && ci < bi[7])) {
#pragma unroll
                for (int j = 0; j < 8; ++j) {
                    bool bet = (cv > bv[j]) || (cv == bv[j] && ci < bi[j]);
                    if (bet) {
                        float tv = bv[j]; int ti = bi[j];
                        bv[j] = cv; bi[j] = ci;
                        cv = tv; ci = ti;
                    }
                }
            }
        }
    }
    for (int i = (n4 << 2) + t; i < N; i += TK_THREADS) {
        float cv = sims[i];
        int   ci = i;
        if (cv > bv[7] || (cv == bv[7] && ci < bi[7])) {
#pragma unroll
            for (int j = 0; j < 8; ++j) {
                bool bet = (cv > bv[j]) || (cv == bv[j] && ci < bi[j]);
                if (bet) {
                    float tv = bv[j]; int ti = bi[j];
                    bv[j] = cv; bi[j] = ci;
                    cv = tv; ci = ti;
                }
            }
        }
    }

#pragma unroll
    for (int j = 0; j < 8; ++j) { lv[t * 8 + j] = bv[j]; li[t * 8 + j] = bi[j]; }

    int taken = 0;
    for (int k = 0; k < K; ++k) {
        __syncthreads();
        float cv = (taken < 8) ? lv[t * 8 + taken] : -INFINITY;
        int   ci = (taken < 8) ? li[t * 8 + taken] : 0x7fffffff;
#pragma unroll
        for (int off = 32; off; off >>= 1) {
            float ov = __shfl_down(cv, off);
            int   oi = __shfl_down(ci, off);
            if (ov > cv || (ov == cv && oi < ci)) { cv = ov; ci = oi; }
        }
        if (lane == 0) { wbv[wid] = cv; wbi[wid] = ci; }
        __syncthreads();
        if (wid == 0) {
            cv = (lane < TK_THREADS / 64) ? wbv[lane] : -INFINITY;
            ci = (lane < TK_THREADS / 64) ? wbi[lane] : 0x7fffffff;
#pragma unroll
            for (int off = TK_THREADS / 128; off; off >>= 1) {
                float ov = __shfl_down(cv, off);
                int   oi = __shfl_down(ci, off);
                if (ov > cv || (ov == cv && oi < ci)) { cv = ov; ci = oi; }
            }
            if (lane == 0) { winner = ci; res[k] = ci; }
        }
        __syncthreads();
        if (taken < 8 && li[t * 8 + taken] == winner) taken++;
    }
    __syncthreads();

    if (t < K * A) {
        int k = t / A, a = t % A;
        out[t] = actions[(size_t)res[k] * A + a];
    }
}

extern "C" void kernel_launch(void* const* d_in, const int* in_sizes, int n_in,
                              void* d_out, int out_size, void* d_ws, size_t ws_size,
                              hipStream_t stream) {
    const float* q       = (const float*)d_in[0];
    const float* keys    = (const float*)d_in[1];
    const float* actions = (const float*)d_in[2];
    float* out = (float*)d_out;

    const int D = in_sizes[0];
    const int N = in_sizes[1] / D;
    const int A = in_sizes[2] / N;     // 7
    const int K = out_size / A;        // 8

    // ws layout: [0] qnorm, [64..] sims[N]
    float* qn   = (float*)d_ws;
    float* sims = (float*)d_ws + 64;

    hipLaunchKernelGGL(qnorm_kernel, dim3(1), dim3(256), 0, stream, q, D, qn);
    if (D == 2048) {
        hipLaunchKernelGGL(sims2048_kernel, dim3(2048), dim3(256), 0, stream,
                           q, keys, qn, sims, N);
    } else {
        hipLaunchKernelGGL(sims_generic_kernel, dim3(1024), dim3(256), 0, stream,
                           q, keys, qn, sims, N, D);
    }
    hipLaunchKernelGGL(topk_kernel, dim3(1), dim3(TK_THREADS), 0, stream,
                       sims, actions, out, N, A, K);
}